// Round 7
// baseline (423.265 us; speedup 1.0000x reference)
//
#include <hip/hip_runtime.h>

#define HW   1024
#define DHW  16384

typedef __attribute__((ext_vector_type(8))) short short8;
typedef __attribute__((ext_vector_type(4))) float f32x4;

static __device__ __forceinline__ ushort f2bf(float f) {
  unsigned u = __float_as_uint(f);
  unsigned r = (u + 0x7fffu + ((u >> 16) & 1u)) >> 16;
  return (ushort)r;
}
static __device__ __forceinline__ float bf2f(ushort u) {
  return __uint_as_float(((unsigned)u) << 16);
}
static __device__ __forceinline__ void async_copy16(const ushort* g, ushort* l) {
  __builtin_amdgcn_global_load_lds(
      (const __attribute__((address_space(1))) unsigned int*)g,
      (__attribute__((address_space(3))) unsigned int*)l, 16, 0, 0);
}

// ---------------------------------------------------------------------------
// k/q 1x1x1 conv, fused with x->xt bf16 repack (xprep eliminated: kq already
// streams all of x; emit xt2[b][z][chunk][hw][8c] as a side product).
// ---------------------------------------------------------------------------
__global__ __launch_bounds__(256) void kq_kernel(
    const float* __restrict__ x, const float* __restrict__ wk,
    const float* __restrict__ bk, const float* __restrict__ wq,
    const float* __restrict__ bq, float* __restrict__ k, float* __restrict__ q,
    ushort* __restrict__ xt) {
  __shared__ float wks[16 * 128];
  __shared__ float wqs[16 * 128];
  int tid = threadIdx.x;
  for (int i = tid; i < 2048; i += 256) { wks[i] = wk[i]; wqs[i] = wq[i]; }
  __syncthreads();
  int b = blockIdx.y;
  int p = blockIdx.x * 256 + tid;
  int z = p >> 10, hw = p & 1023;
  float ak[16], aq[16];
#pragma unroll
  for (int o = 0; o < 16; ++o) { ak[o] = 0.f; aq[o] = 0.f; }
  const float* xb = x + (size_t)b * 128 * DHW + p;
  ushort* xtp = xt + (((size_t)(b * 16 + z) * 16) * 1024 + hw) * 8;
  for (int chunk = 0; chunk < 16; ++chunk) {
    ushort pack[8];
#pragma unroll
    for (int c8 = 0; c8 < 8; ++c8) {
      int c = chunk * 8 + c8;
      float xv = xb[(size_t)c * DHW];
      pack[c8] = f2bf(xv);
#pragma unroll
      for (int o = 0; o < 16; ++o) {
        ak[o] += wks[o * 128 + c] * xv;
        aq[o] += wqs[o * 128 + c] * xv;
      }
    }
    *(uint4*)&xtp[(size_t)chunk * 1024 * 8] = *(const uint4*)pack;
  }
#pragma unroll
  for (int o = 0; o < 16; ++o) {
    k[((size_t)b * 16 + o) * DHW + p] = ak[o] + bk[o];
    q[((size_t)b * 16 + o) * DHW + p] = aq[o] + bq[o];
  }
}

// ---------------------------------------------------------------------------
// weight prep: wt2[kd][chunk(16)][tap(9)][o(128)][8c] <- wv[o][c][kd,kh,kw]
// ---------------------------------------------------------------------------
__global__ __launch_bounds__(256) void wprep_kernel(
    const float* __restrict__ wv, ushort* __restrict__ wt,
    ushort* __restrict__ zbuf) {
  if (blockIdx.x == 0 && threadIdx.x < 512) zbuf[threadIdx.x] = 0;
  int i = blockIdx.x * 256 + threadIdx.x;
  if (i >= 27 * 128 * 128) return;
  int c8 = i & 7;
  int t = i >> 3;
  int o = t & 127; t >>= 7;
  int tap = t % 9; t /= 9;
  int chunk = t & 15;
  int kd = t >> 4;
  wt[i] = f2bf(wv[(size_t)(o * 128 + chunk * 8 + c8) * 27 + kd * 9 + tap]);
}

// ---------------------------------------------------------------------------
// v 3x3x3 conv as implicit-GEMM bf16 MFMA. v7: h-tile 16 (was 8) -- doubles
// MFMA per staged byte (wsm 36KB amortized over 2x output rows): fill/compute
// per phase 60KB/2800cyc -> 77KB/5587cyc. Grid (128 bz, 2 h, 2 o) = 512
// blocks = 2/CU (LDS 77.8KB x2 = 152KB <= 160). acc[4][8].
// b = bz&7 so XCD = b (v4 swizzle kept). Cross-block overlap provides the
// stage/MFMA pipelining (m114); intra-block dbuf regressed (r5).
// ---------------------------------------------------------------------------
__global__ __launch_bounds__(256, 2) void vconv_mfma_kernel(
    const ushort* __restrict__ xt, const ushort* __restrict__ wt,
    const float* __restrict__ bv, const ushort* __restrict__ zbuf,
    ushort* __restrict__ v) {
  __shared__ __align__(16) ushort xs[2560 * 8];    // 40 KB (2448 used + pad)
  __shared__ __align__(16) ushort wsm[2304 * 8];   // 36 KB
  int tid = threadIdx.x;
  int wave = tid >> 6;
  int ml = tid & 15;
  int quad = (tid >> 4) & 3;
  int bz = blockIdx.x;
  int b = bz & 7, z = bz >> 3;           // XCD-locality decode (v4)
  int h0 = blockIdx.y * 16;
  int o0 = blockIdx.z * 64;

  f32x4 acc[4][8];
#pragma unroll
  for (int s = 0; s < 4; ++s)
#pragma unroll
    for (int t = 0; t < 8; ++t) acc[s][t] = (f32x4){0.f, 0.f, 0.f, 0.f};

  // wave owns output rows h0 + wave*4 .. +3; t = (row, w-half)
  int cb0[8];
#pragma unroll
  for (int t = 0; t < 8; ++t)
    cb0[t] = (wave * 4 + (t >> 1)) * 34 + (t & 1) * 16 + ml;

  // x tile: 4 channels x 18 rows x 34 cols = 2448 cells (+pad to 2560)
  int xoff[10]; bool okx[10];
#pragma unroll
  for (int it = 0; it < 10; ++it) {
    int i = it * 256 + tid;
    int cu = i / 612;
    int cell = i - cu * 612;
    int hr = cell / 34;
    int wc = cell - hr * 34;
    int h = h0 + hr - 1, ww = wc - 1;
    okx[it] = (i < 2448) && ((unsigned)h < 32u) && ((unsigned)ww < 32u);
    xoff[it] = cu * 1024 + h * 32 + ww;
  }
  int woff[9];
#pragma unroll
  for (int it = 0; it < 9; ++it) {
    int i = it * 256 + tid;
    int cu = i / 576;
    int r = i - cu * 576;
    int tap = r >> 6, ol = r & 63;
    woff[it] = (cu * 9 + tap) * 128 + o0 + ol;
  }

  const int KH[9] = {0, 0, 0, 1, 1, 1, 2, 2, 2};
  const int KW[9] = {0, 1, 2, 0, 1, 2, 0, 1, 2};

  for (int kd = 0; kd < 3; ++kd) {
    int zd = z + kd - 1;
    bool zok = (zd >= 0 && zd < 16);
    int zdc = zok ? zd : 0;
    const ushort* xbase = xt + (size_t)(b * 16 + zdc) * 16 * 1024 * 8;
    for (int cb = 0; cb < 4; ++cb) {
      const ushort* xsb = xbase + (size_t)cb * 4 * 1024 * 8;
      const ushort* wsb = wt + (size_t)(kd * 16 + cb * 4) * 9 * 128 * 8;
#pragma unroll
      for (int it = 0; it < 10; ++it) {
        const ushort* g = (zok && okx[it]) ? xsb + (size_t)xoff[it] * 8 : zbuf;
        async_copy16(g, &xs[(it * 256 + tid) * 8]);
      }
#pragma unroll
      for (int it = 0; it < 9; ++it)
        async_copy16(wsb + (size_t)woff[it] * 8, &wsm[(it * 256 + tid) * 8]);
      __syncthreads();
#pragma unroll
      for (int tap = 0; tap < 9; ++tap) {
        const int kh = KH[tap], kw = KW[tap];
        short8 af[4], bfr[8];
#pragma unroll
        for (int s = 0; s < 4; ++s)
          af[s] = *(const short8*)&wsm[(quad * 576 + tap * 64 + s * 16 + ml) * 8];
#pragma unroll
        for (int t = 0; t < 8; ++t) {
          int cell = cb0[t] + kh * 34 + kw;
          bfr[t] = *(const short8*)&xs[(quad * 612 + cell) * 8];
        }
#pragma unroll
        for (int s = 0; s < 4; ++s)
#pragma unroll
          for (int t = 0; t < 8; ++t)
            acc[s][t] = __builtin_amdgcn_mfma_f32_16x16x32_bf16(af[s], bfr[t], acc[s][t], 0, 0, 0);
      }
      __syncthreads();
    }
  }
#pragma unroll
  for (int s = 0; s < 4; ++s) {
    int o = o0 + s * 16 + quad * 4;
#pragma unroll
    for (int t = 0; t < 8; ++t) {
      int pl = wave * 128 + t * 16 + ml;
      ushort* dst = &v[((size_t)(b * 128 + o) * 16 + z) * 1024 + h0 * 32 + pl];
#pragma unroll
      for (int r = 0; r < 4; ++r)
        dst[(size_t)r * 16384] = f2bf(acc[s][t][r] + bv[o + r]);
    }
  }
}

// ---------------------------------------------------------------------------
// kqt: transpose k,q (fp32 [b][o][z][hw]) -> bf16 kT/qT [b][hw][f=o*16+z]
// via LDS tiles; also zeroes rsum (runs after vconv, before apx).
// ---------------------------------------------------------------------------
__global__ __launch_bounds__(256) void kqt_kernel(
    const float* __restrict__ k, const float* __restrict__ q,
    ushort* __restrict__ kT, ushort* __restrict__ qT,
    float* __restrict__ rsum) {
  __shared__ __align__(16) ushort tile[32 * 264];
  int tid = threadIdx.x;
  int t0 = blockIdx.x;   // hw tile 0..31
  int b = blockIdx.y;    // 0..7
  if (t0 == 0)
    *(float4*)&rsum[b * 1024 + tid * 4] = (float4){0.f, 0.f, 0.f, 0.f};
  int h0 = t0 * 32;

  // ---- k pass
  {
    const float* s = k + (size_t)b * 16 * DHW;
    for (int it = 0; it < 32; ++it) {
      int i = it * 256 + tid;
      int oo = i >> 9, zz = (i >> 5) & 15, hl = i & 31;
      tile[hl * 264 + oo * 16 + zz] =
          f2bf(s[(size_t)oo * DHW + zz * 1024 + h0 + hl]);
    }
    __syncthreads();
    ushort* d = kT + ((size_t)b * 1024 + h0) * 256;
    for (int jt = 0; jt < 4; ++jt) {
      int j = jt * 256 + tid;
      int hl = j >> 5, c8 = (j & 31) * 8;
      *(uint4*)&d[(size_t)hl * 256 + c8] = *(const uint4*)&tile[hl * 264 + c8];
    }
    __syncthreads();
  }
  // ---- q pass
  {
    const float* s = q + (size_t)b * 16 * DHW;
    for (int it = 0; it < 32; ++it) {
      int i = it * 256 + tid;
      int oo = i >> 9, zz = (i >> 5) & 15, hl = i & 31;
      tile[hl * 264 + oo * 16 + zz] =
          f2bf(s[(size_t)oo * DHW + zz * 1024 + h0 + hl]);
    }
    __syncthreads();
    ushort* d = qT + ((size_t)b * 1024 + h0) * 256;
    for (int jt = 0; jt < 4; ++jt) {
      int j = jt * 256 + tid;
      int hl = j >> 5, c8 = (j & 31) * 8;
      *(uint4*)&d[(size_t)hl * 256 + c8] = *(const uint4*)&tile[hl * 264 + c8];
    }
  }
}

// ---------------------------------------------------------------------------
// apx: S = K^T Q (K-dim f=256) via bf16 MFMA (combine's verified dbuf loop,
// strides 256, 4 K-steps). Softmax without max-subtraction; stores
// unnormalized P = exp(S) bf16 + row sums via atomicAdd; combine divides.
// Grid (8 b, 64 tiles): XCD = b.
// ---------------------------------------------------------------------------
__global__ __launch_bounds__(256, 2) void apx_kernel(
    const ushort* __restrict__ kT, const ushort* __restrict__ qT,
    ushort* __restrict__ A_p, float* __restrict__ rsum) {
  __shared__ __align__(16) ushort smem[32768];
  int tid = threadIdx.x;
  int wave = tid >> 6, lane = tid & 63;
  int ml = lane & 15, quad = lane >> 4;
  int wm = wave >> 1, wj = wave & 1;
  int b = blockIdx.x;
  int tile = blockIdx.y;
  int m0 = (tile >> 3) * 128;   // s-rows (softmax rows)
  int j0 = (tile & 7) * 128;    // t-cols

  f32x4 acc[4][4];
#pragma unroll
  for (int s = 0; s < 4; ++s)
#pragma unroll
    for (int t = 0; t < 4; ++t) acc[s][t] = (f32x4){0.f, 0.f, 0.f, 0.f};

  const ushort* va = kT + ((size_t)b * 1024 + m0) * 256;
  const ushort* pa = qT + ((size_t)b * 1024 + j0) * 256;

  int srow[4], skc[4];
#pragma unroll
  for (int n = 0; n < 4; ++n) {
    int slot = wave * 256 + n * 64 + lane;
    srow[n] = slot >> 3;
    skc[n] = (slot & 7) ^ (srow[n] & 7);
  }

  // prologue: K-step 0 -> buffer 0
#pragma unroll
  for (int n = 0; n < 4; ++n) {
    async_copy16(va + (size_t)srow[n] * 256 + skc[n] * 8,
                 &smem[(wave * 256 + n * 64) * 8]);
    async_copy16(pa + (size_t)srow[n] * 256 + skc[n] * 8,
                 &smem[8192 + (wave * 256 + n * 64) * 8]);
  }
  __syncthreads();

  for (int t = 0; t < 4; ++t) {
    int cur = (t & 1) * 16384;
    int nxt = 16384 - cur;
    if (t < 3) {
      int kk = (t + 1) * 64;
#pragma unroll
      for (int n = 0; n < 4; ++n) {
        async_copy16(va + (size_t)srow[n] * 256 + kk + skc[n] * 8,
                     &smem[nxt + (wave * 256 + n * 64) * 8]);
        async_copy16(pa + (size_t)srow[n] * 256 + kk + skc[n] * 8,
                     &smem[nxt + 8192 + (wave * 256 + n * 64) * 8]);
      }
    }
#pragma unroll
    for (int ks = 0; ks < 2; ++ks) {
      short8 af[4], bfr[4];
#pragma unroll
      for (int s = 0; s < 4; ++s) {
        int row = wm * 64 + s * 16 + ml;
        int c = ks * 4 + quad;
        af[s] = *(const short8*)&smem[cur + (row * 8 + (c ^ (row & 7))) * 8];
      }
#pragma unroll
      for (int t2 = 0; t2 < 4; ++t2) {
        int row = wj * 64 + t2 * 16 + ml;
        int c = ks * 4 + quad;
        bfr[t2] = *(const short8*)&smem[cur + 8192 + (row * 8 + (c ^ (row & 7))) * 8];
      }
#pragma unroll
      for (int s = 0; s < 4; ++s)
#pragma unroll
        for (int t2 = 0; t2 < 4; ++t2)
          acc[s][t2] = __builtin_amdgcn_mfma_f32_16x16x32_bf16(af[s], bfr[t2], acc[s][t2], 0, 0, 0);
    }
    __syncthreads();
  }

  // ---- epilogue: P = exp(S); partial row sums over this block's 128 cols
#pragma unroll
  for (int s = 0; s < 4; ++s)
#pragma unroll
    for (int r = 0; r < 4; ++r) {
      float sum = 0.f;
#pragma unroll
      for (int t2 = 0; t2 < 4; ++t2) {
        float p = __expf(acc[s][t2][r]);
        acc[s][t2][r] = p;
        sum += p;
      }
      sum += __shfl_xor(sum, 1);
      sum += __shfl_xor(sum, 2);
      sum += __shfl_xor(sum, 4);
      sum += __shfl_xor(sum, 8);
      if (ml == 0) {
        int m = m0 + wm * 64 + s * 16 + quad * 4 + r;
        atomicAdd(&rsum[b * 1024 + m], sum);
      }
    }
  // store unnormalized P (bf16)
#pragma unroll
  for (int s = 0; s < 4; ++s)
#pragma unroll
    for (int t2 = 0; t2 < 4; ++t2) {
      int j = j0 + wj * 64 + t2 * 16 + ml;
#pragma unroll
      for (int r = 0; r < 4; ++r) {
        int m = m0 + wm * 64 + s * 16 + quad * 4 + r;
        A_p[((size_t)b * 1024 + m) * 1024 + j] = f2bf(acc[s][t2][r]);
      }
    }
}

// ---------------------------------------------------------------------------
// A_d depth attention softmax
// ---------------------------------------------------------------------------
__global__ __launch_bounds__(256) void ad_kernel(
    const float* __restrict__ k, const float* __restrict__ q,
    float* __restrict__ A_d) {
  int tid = threadIdx.x;
  int b = blockIdx.x >> 4;
  int dj = blockIdx.x & 15;
  float acc[16];
#pragma unroll
  for (int e = 0; e < 16; ++e) acc[e] = 0.f;
  const float* kb = k + (size_t)b * 256 * HW;
  const float* qb = q + (size_t)b * 256 * HW;
  for (int f = tid; f < 16384; f += 256) {
    int oc = f >> 10, hw = f & 1023;
    float kv = kb[(oc * 16 + dj) * HW + hw];
#pragma unroll
    for (int e = 0; e < 16; ++e)
      acc[e] += kv * qb[(oc * 16 + e) * HW + hw];
  }
  __shared__ float sred[16][4];
  __shared__ float arow[16];
  __shared__ float prow[16];
  int lane = tid & 63, wid = tid >> 6;
#pragma unroll
  for (int e = 0; e < 16; ++e) {
    float s = acc[e];
    for (int off = 32; off >= 1; off >>= 1) s += __shfl_xor(s, off);
    if (lane == 0) sred[e][wid] = s;
  }
  __syncthreads();
  if (tid < 16) arow[tid] = sred[tid][0] + sred[tid][1] + sred[tid][2] + sred[tid][3];
  __syncthreads();
  if (tid < 16) {
    float m = arow[0];
    for (int e = 1; e < 16; ++e) m = fmaxf(m, arow[e]);
    prow[tid] = __expf(arow[tid] - m);
  }
  __syncthreads();
  if (tid < 16) {
    float s = 0.f;
    for (int e = 0; e < 16; ++e) s += prow[e];
    A_d[(size_t)b * 256 + dj * 16 + tid] = prow[tid] / s;
  }
}

// ---------------------------------------------------------------------------
// combine: Patt = vf @ P^T / rowsum via bf16 MFMA + fused Datt + residual.
// v6: acc scaled by 1/rsum[j] (apx stores unnormalized P) before Datt add.
// ---------------------------------------------------------------------------
__global__ __launch_bounds__(256, 2) void combine_mfma_kernel(
    const ushort* __restrict__ vb, const ushort* __restrict__ apb,
    const float* __restrict__ A_d, const float* __restrict__ rsum,
    const float* __restrict__ x, const float* __restrict__ gamma,
    float* __restrict__ out) {
  __shared__ __align__(16) ushort smem[32768];
  __shared__ float Adt[272];  // A_d transposed, padded: Adt[d*17 + dj]
  int tid = threadIdx.x;
  int wave = tid >> 6, lane = tid & 63;
  int ml = lane & 15, quad = lane >> 4;
  int wm = wave >> 1, wj = wave & 1;
  int b = blockIdx.x;                    // XCD = wg_linear % 8 = b
  int tile = blockIdx.y;
  int m0 = (tile >> 3) * 128;            // m outer
  int j0 = (tile & 7) * 128;             // j inner
  Adt[(tid & 15) * 17 + (tid >> 4)] = A_d[b * 256 + tid];

  f32x4 acc[4][4];
#pragma unroll
  for (int s = 0; s < 4; ++s)
#pragma unroll
    for (int t = 0; t < 4; ++t) acc[s][t] = (f32x4){0.f, 0.f, 0.f, 0.f};

  const ushort* va = vb + ((size_t)b * 2048 + m0) * 1024;
  const ushort* pa = apb + ((size_t)b * 1024 + j0) * 1024;

  int srow[4], skc[4];
#pragma unroll
  for (int n = 0; n < 4; ++n) {
    int slot = wave * 256 + n * 64 + lane;
    srow[n] = slot >> 3;
    skc[n] = (slot & 7) ^ (srow[n] & 7);
  }

  // prologue: K-tile 0 -> buffer 0
#pragma unroll
  for (int n = 0; n < 4; ++n) {
    async_copy16(va + (size_t)srow[n] * 1024 + skc[n] * 8,
                 &smem[(wave * 256 + n * 64) * 8]);
    async_copy16(pa + (size_t)srow[n] * 1024 + skc[n] * 8,
                 &smem[8192 + (wave * 256 + n * 64) * 8]);
  }
  __syncthreads();

  for (int t = 0; t < 16; ++t) {
    int cur = (t & 1) * 16384;
    int nxt = 16384 - cur;
    if (t < 15) {
      int kk = (t + 1) * 64;
#pragma unroll
      for (int n = 0; n < 4; ++n) {
        async_copy16(va + (size_t)srow[n] * 1024 + kk + skc[n] * 8,
                     &smem[nxt + (wave * 256 + n * 64) * 8]);
        async_copy16(pa + (size_t)srow[n] * 1024 + kk + skc[n] * 8,
                     &smem[nxt + 8192 + (wave * 256 + n * 64) * 8]);
      }
    }
#pragma unroll
    for (int ks = 0; ks < 2; ++ks) {
      short8 af[4], bfr[4];
#pragma unroll
      for (int s = 0; s < 4; ++s) {
        int row = wm * 64 + s * 16 + ml;
        int c = ks * 4 + quad;
        af[s] = *(const short8*)&smem[cur + (row * 8 + (c ^ (row & 7))) * 8];
      }
#pragma unroll
      for (int t2 = 0; t2 < 4; ++t2) {
        int row = wj * 64 + t2 * 16 + ml;
        int c = ks * 4 + quad;
        bfr[t2] = *(const short8*)&smem[cur + 8192 + (row * 8 + (c ^ (row & 7))) * 8];
      }
#pragma unroll
      for (int s = 0; s < 4; ++s)
#pragma unroll
        for (int t2 = 0; t2 < 4; ++t2)
          acc[s][t2] = __builtin_amdgcn_mfma_f32_16x16x32_bf16(af[s], bfr[t2], acc[s][t2], 0, 0, 0);
    }
    __syncthreads();
  }

  // ---- normalize Patt by softmax row sums (apx stored unnormalized P)
  float invr[4];
#pragma unroll
  for (int t2 = 0; t2 < 4; ++t2)
    invr[t2] = 1.f / rsum[b * 1024 + j0 + wj * 64 + t2 * 16 + ml];
#pragma unroll
  for (int s = 0; s < 4; ++s)
#pragma unroll
    for (int t2 = 0; t2 < 4; ++t2)
#pragma unroll
      for (int r = 0; r < 4; ++r) acc[s][t2][r] *= invr[t2];

  // ---- epilogue: stage v[m0:+128][j0:+128] bf16 into smem (stride 136)
  for (int i = tid; i < 2048; i += 256) {
    int row = i >> 4, jc = i & 15;
    uint4 val = *(const uint4*)&vb[((size_t)b * 2048 + m0 + row) * 1024 + j0 + jc * 8];
    *(uint4*)&smem[row * 136 + jc * 8] = val;
  }
  __syncthreads();

  // Datt accumulated directly into acc; d-outer, conflict-free Adt.
#pragma unroll
  for (int d = 0; d < 16; ++d) {
    float ar[4];
#pragma unroll
    for (int r = 0; r < 4; ++r) ar[r] = Adt[d * 17 + quad * 4 + r];
#pragma unroll
    for (int s = 0; s < 4; ++s) {
      const ushort* vrow = &smem[(wm * 64 + s * 16 + d) * 136];
#pragma unroll
      for (int t2 = 0; t2 < 4; ++t2) {
        float vv = bf2f(vrow[wj * 64 + t2 * 16 + ml]);
#pragma unroll
        for (int r = 0; r < 4; ++r) acc[s][t2][r] += ar[r] * vv;
      }
    }
  }

  float g = gamma[0];
#pragma unroll
  for (int s = 0; s < 4; ++s) {
#pragma unroll
    for (int t2 = 0; t2 < 4; ++t2) {
      int jrel = wj * 64 + t2 * 16 + ml;
#pragma unroll
      for (int r = 0; r < 4; ++r) {
        int m = m0 + wm * 64 + s * 16 + quad * 4 + r;
        size_t idx = ((size_t)b * 2048 + m) * 1024 + j0 + jrel;
        out[idx] = g * acc[s][t2][r] + x[idx];
      }
    }
  }
}

// ---------------------------------------------------------------------------
extern "C" void kernel_launch(void* const* d_in, const int* in_sizes, int n_in,
                              void* d_out, int out_size, void* d_ws, size_t ws_size,
                              hipStream_t stream) {
  const float* x     = (const float*)d_in[0];
  const float* gamma = (const float*)d_in[1];
  const float* w_k   = (const float*)d_in[2];
  const float* b_k   = (const float*)d_in[3];
  const float* w_q   = (const float*)d_in[4];
  const float* b_q   = (const float*)d_in[5];
  const float* w_v   = (const float*)d_in[6];
  const float* b_v   = (const float*)d_in[7];
  float* out = (float*)d_out;

  float* k    = (float*)d_ws;            // 2,097,152 f32
  float* q    = k + 2097152;             // 2,097,152 f32
  float* A_d  = q + 2097152;             // 2,048 f32
  ushort* vbf = (ushort*)(A_d + 2048);   // 16,777,216 bf16
  ushort* apb = vbf + 16777216;          // 8,388,608 bf16
  ushort* wt  = apb + 8388608;           // 442,368 bf16
  ushort* zbuf = wt + 442368;            // 512 bf16 zeros
  ushort* xt  = zbuf + 512;              // 16,777,216 bf16
  // xt region is dead after vconv -> reuse for kT/qT/rsum (written by kqt):
  ushort* kT16 = xt;                     // 2,097,152 bf16
  ushort* qT16 = xt + 2097152;           // 2,097,152 bf16
  float* rsum  = (float*)(xt + 4194304); // 8,192 f32

  wprep_kernel<<<dim3(1728), 256, 0, stream>>>(w_v, wt, zbuf);
  kq_kernel<<<dim3(64, 8), 256, 0, stream>>>(x, w_k, b_k, w_q, b_q, k, q, xt);
  vconv_mfma_kernel<<<dim3(128, 2, 2), 256, 0, stream>>>(xt, wt, b_v, zbuf, vbf);
  kqt_kernel<<<dim3(32, 8), 256, 0, stream>>>(k, q, kT16, qT16, rsum);
  apx_kernel<<<dim3(8, 64), 256, 0, stream>>>(kT16, qT16, apb, rsum);
  ad_kernel<<<dim3(128), 256, 0, stream>>>(k, q, A_d);
  combine_mfma_kernel<<<dim3(8, 128), 256, 0, stream>>>(vbf, apb, A_d, rsum, x, gamma, out);
}

// Round 8
// 373.995 us; speedup vs baseline: 1.1317x; 1.1317x over previous
//
#include <hip/hip_runtime.h>

#define HW   1024
#define DHW  16384

typedef __attribute__((ext_vector_type(8))) short short8;
typedef __attribute__((ext_vector_type(4))) float f32x4;

static __device__ __forceinline__ ushort f2bf(float f) {
  unsigned u = __float_as_uint(f);
  unsigned r = (u + 0x7fffu + ((u >> 16) & 1u)) >> 16;
  return (ushort)r;
}
static __device__ __forceinline__ float bf2f(ushort u) {
  return __uint_as_float(((unsigned)u) << 16);
}
static __device__ __forceinline__ void async_copy16(const ushort* g, ushort* l) {
  __builtin_amdgcn_global_load_lds(
      (const __attribute__((address_space(1))) unsigned int*)g,
      (__attribute__((address_space(3))) unsigned int*)l, 16, 0, 0);
}

// ---------------------------------------------------------------------------
// k/q 1x1x1 conv, fused with x->xt bf16 repack (xprep eliminated).
// ---------------------------------------------------------------------------
__global__ __launch_bounds__(256) void kq_kernel(
    const float* __restrict__ x, const float* __restrict__ wk,
    const float* __restrict__ bk, const float* __restrict__ wq,
    const float* __restrict__ bq, float* __restrict__ k, float* __restrict__ q,
    ushort* __restrict__ xt) {
  __shared__ float wks[16 * 128];
  __shared__ float wqs[16 * 128];
  int tid = threadIdx.x;
  for (int i = tid; i < 2048; i += 256) { wks[i] = wk[i]; wqs[i] = wq[i]; }
  __syncthreads();
  int b = blockIdx.y;
  int p = blockIdx.x * 256 + tid;
  int z = p >> 10, hw = p & 1023;
  float ak[16], aq[16];
#pragma unroll
  for (int o = 0; o < 16; ++o) { ak[o] = 0.f; aq[o] = 0.f; }
  const float* xb = x + (size_t)b * 128 * DHW + p;
  ushort* xtp = xt + (((size_t)(b * 16 + z) * 16) * 1024 + hw) * 8;
  for (int chunk = 0; chunk < 16; ++chunk) {
    ushort pack[8];
#pragma unroll
    for (int c8 = 0; c8 < 8; ++c8) {
      int c = chunk * 8 + c8;
      float xv = xb[(size_t)c * DHW];
      pack[c8] = f2bf(xv);
#pragma unroll
      for (int o = 0; o < 16; ++o) {
        ak[o] += wks[o * 128 + c] * xv;
        aq[o] += wqs[o * 128 + c] * xv;
      }
    }
    *(uint4*)&xtp[(size_t)chunk * 1024 * 8] = *(const uint4*)pack;
  }
#pragma unroll
  for (int o = 0; o < 16; ++o) {
    k[((size_t)b * 16 + o) * DHW + p] = ak[o] + bk[o];
    q[((size_t)b * 16 + o) * DHW + p] = aq[o] + bq[o];
  }
}

// ---------------------------------------------------------------------------
// weight prep: wt2[kd][chunk(16)][tap(9)][o(128)][8c] <- wv[o][c][kd,kh,kw]
// ---------------------------------------------------------------------------
__global__ __launch_bounds__(256) void wprep_kernel(
    const float* __restrict__ wv, ushort* __restrict__ wt,
    ushort* __restrict__ zbuf) {
  if (blockIdx.x == 0 && threadIdx.x < 512) zbuf[threadIdx.x] = 0;
  int i = blockIdx.x * 256 + threadIdx.x;
  if (i >= 27 * 128 * 128) return;
  int c8 = i & 7;
  int t = i >> 3;
  int o = t & 127; t >>= 7;
  int tap = t % 9; t /= 9;
  int chunk = t & 15;
  int kd = t >> 4;
  wt[i] = f2bf(wv[(size_t)(o * 128 + chunk * 8 + c8) * 27 + kd * 9 + tap]);
}

// ---------------------------------------------------------------------------
// v 3x3x3 conv as implicit-GEMM bf16 MFMA (round-6 version: acc[4][4],
// grid (128,4,2), 2 blocks/CU -- the verified 99.4us config).
// b = bz&7 so XCD = b. Cross-block overlap provides stage/MFMA pipelining
// (m114); intra-block dbuf regressed (r5: barrier drains vmcnt); bigger
// acc tiles regressed (r7: 256-reg ceiling -> scratch spill, WRITE 2x).
// SQ_LDS_BANK_CONFLICT ~7.1M here is the intrinsic ~2cyc/wave-b128 floor,
// not fixable aliasing (exact decomposition: 12ph x 9tap x 8reads x 4w x 2).
// ---------------------------------------------------------------------------
__global__ __launch_bounds__(256, 2) void vconv_mfma_kernel(
    const ushort* __restrict__ xt, const ushort* __restrict__ wt,
    const float* __restrict__ bv, const ushort* __restrict__ zbuf,
    ushort* __restrict__ v) {
  __shared__ __align__(16) ushort xs[1536 * 8];
  __shared__ __align__(16) ushort wsm[2304 * 8];
  int tid = threadIdx.x;
  int wave = tid >> 6;
  int ml = tid & 15;
  int quad = (tid >> 4) & 3;
  int bz = blockIdx.x;
  int b = bz & 7, z = bz >> 3;           // XCD-locality decode (v4)
  int h0 = blockIdx.y * 8;
  int o0 = blockIdx.z * 64;

  f32x4 acc[4][4];
#pragma unroll
  for (int s = 0; s < 4; ++s)
#pragma unroll
    for (int t = 0; t < 4; ++t) acc[s][t] = (f32x4){0.f, 0.f, 0.f, 0.f};

  int cb0[4];
#pragma unroll
  for (int t = 0; t < 4; ++t)
    cb0[t] = (wave * 2 + (t >> 1)) * 34 + (t & 1) * 16 + ml;

  int xoff[6]; bool okx[6];
#pragma unroll
  for (int it = 0; it < 6; ++it) {
    int i = it * 256 + tid;
    int cu = i / 340;
    int cell = i - cu * 340;
    int hr = cell / 34;
    int wc = cell - hr * 34;
    int h = h0 + hr - 1, ww = wc - 1;
    okx[it] = (i < 1360) && ((unsigned)h < 32u) && ((unsigned)ww < 32u);
    xoff[it] = cu * 1024 + h * 32 + ww;
  }
  int woff[9];
#pragma unroll
  for (int it = 0; it < 9; ++it) {
    int i = it * 256 + tid;
    int cu = i / 576;
    int r = i - cu * 576;
    int tap = r >> 6, ol = r & 63;
    woff[it] = (cu * 9 + tap) * 128 + o0 + ol;
  }

  const int KH[9] = {0, 0, 0, 1, 1, 1, 2, 2, 2};
  const int KW[9] = {0, 1, 2, 0, 1, 2, 0, 1, 2};

  for (int kd = 0; kd < 3; ++kd) {
    int zd = z + kd - 1;
    bool zok = (zd >= 0 && zd < 16);
    int zdc = zok ? zd : 0;
    const ushort* xbase = xt + (size_t)(b * 16 + zdc) * 16 * 1024 * 8;
    for (int cb = 0; cb < 4; ++cb) {
      const ushort* xsb = xbase + (size_t)cb * 4 * 1024 * 8;
      const ushort* wsb = wt + (size_t)(kd * 16 + cb * 4) * 9 * 128 * 8;
#pragma unroll
      for (int it = 0; it < 6; ++it) {
        const ushort* g = (zok && okx[it]) ? xsb + (size_t)xoff[it] * 8 : zbuf;
        async_copy16(g, &xs[(it * 256 + tid) * 8]);
      }
#pragma unroll
      for (int it = 0; it < 9; ++it)
        async_copy16(wsb + (size_t)woff[it] * 8, &wsm[(it * 256 + tid) * 8]);
      __syncthreads();
#pragma unroll
      for (int tap = 0; tap < 9; ++tap) {
        const int kh = KH[tap], kw = KW[tap];
        short8 af[4], bfr[4];
#pragma unroll
        for (int s = 0; s < 4; ++s)
          af[s] = *(const short8*)&wsm[(quad * 576 + tap * 64 + s * 16 + ml) * 8];
#pragma unroll
        for (int t = 0; t < 4; ++t) {
          int cell = cb0[t] + kh * 34 + kw;
          bfr[t] = *(const short8*)&xs[(quad * 340 + cell) * 8];
        }
#pragma unroll
        for (int s = 0; s < 4; ++s)
#pragma unroll
          for (int t = 0; t < 4; ++t)
            acc[s][t] = __builtin_amdgcn_mfma_f32_16x16x32_bf16(af[s], bfr[t], acc[s][t], 0, 0, 0);
      }
      __syncthreads();
    }
  }
#pragma unroll
  for (int s = 0; s < 4; ++s) {
    int o = o0 + s * 16 + quad * 4;
#pragma unroll
    for (int t = 0; t < 4; ++t) {
      int pl = wave * 64 + t * 16 + ml;
      ushort* dst = &v[((size_t)(b * 128 + o) * 16 + z) * 1024 + h0 * 32 + pl];
#pragma unroll
      for (int r = 0; r < 4; ++r)
        dst[(size_t)r * 16384] = f2bf(acc[s][t][r] + bv[o + r]);
    }
  }
}

// ---------------------------------------------------------------------------
// kqt: transpose k,q (fp32 [b][o][z][hw]) -> bf16 kT/qT [b][hw][f=o*16+z]
// via LDS tiles; zeroes rsum and Sd (runs after vconv, before apx/ad_part).
// ---------------------------------------------------------------------------
__global__ __launch_bounds__(256) void kqt_kernel(
    const float* __restrict__ k, const float* __restrict__ q,
    ushort* __restrict__ kT, ushort* __restrict__ qT,
    float* __restrict__ rsum, float* __restrict__ Sd) {
  __shared__ __align__(16) ushort tile[32 * 264];
  int tid = threadIdx.x;
  int t0 = blockIdx.x;   // hw tile 0..31
  int b = blockIdx.y;    // 0..7
  if (t0 == 0) {
    *(float4*)&rsum[b * 1024 + tid * 4] = (float4){0.f, 0.f, 0.f, 0.f};
    Sd[b * 256 + tid] = 0.f;
  }
  int h0 = t0 * 32;

  // ---- k pass
  {
    const float* s = k + (size_t)b * 16 * DHW;
    for (int it = 0; it < 32; ++it) {
      int i = it * 256 + tid;
      int oo = i >> 9, zz = (i >> 5) & 15, hl = i & 31;
      tile[hl * 264 + oo * 16 + zz] =
          f2bf(s[(size_t)oo * DHW + zz * 1024 + h0 + hl]);
    }
    __syncthreads();
    ushort* d = kT + ((size_t)b * 1024 + h0) * 256;
    for (int jt = 0; jt < 4; ++jt) {
      int j = jt * 256 + tid;
      int hl = j >> 5, c8 = (j & 31) * 8;
      *(uint4*)&d[(size_t)hl * 256 + c8] = *(const uint4*)&tile[hl * 264 + c8];
    }
    __syncthreads();
  }
  // ---- q pass
  {
    const float* s = q + (size_t)b * 16 * DHW;
    for (int it = 0; it < 32; ++it) {
      int i = it * 256 + tid;
      int oo = i >> 9, zz = (i >> 5) & 15, hl = i & 31;
      tile[hl * 264 + oo * 16 + zz] =
          f2bf(s[(size_t)oo * DHW + zz * 1024 + h0 + hl]);
    }
    __syncthreads();
    ushort* d = qT + ((size_t)b * 1024 + h0) * 256;
    for (int jt = 0; jt < 4; ++jt) {
      int j = jt * 256 + tid;
      int hl = j >> 5, c8 = (j & 31) * 8;
      *(uint4*)&d[(size_t)hl * 256 + c8] = *(const uint4*)&tile[hl * 264 + c8];
    }
  }
}

// ---------------------------------------------------------------------------
// apx: S = K^T Q (K-dim f=256) via bf16 MFMA (combine's verified dbuf loop).
// Stores unnormalized P = exp(S) bf16 + row sums via atomicAdd.
// ---------------------------------------------------------------------------
__global__ __launch_bounds__(256, 2) void apx_kernel(
    const ushort* __restrict__ kT, const ushort* __restrict__ qT,
    ushort* __restrict__ A_p, float* __restrict__ rsum) {
  __shared__ __align__(16) ushort smem[32768];
  int tid = threadIdx.x;
  int wave = tid >> 6, lane = tid & 63;
  int ml = lane & 15, quad = lane >> 4;
  int wm = wave >> 1, wj = wave & 1;
  int b = blockIdx.x;
  int tile = blockIdx.y;
  int m0 = (tile >> 3) * 128;   // s-rows (softmax rows)
  int j0 = (tile & 7) * 128;    // t-cols

  f32x4 acc[4][4];
#pragma unroll
  for (int s = 0; s < 4; ++s)
#pragma unroll
    for (int t = 0; t < 4; ++t) acc[s][t] = (f32x4){0.f, 0.f, 0.f, 0.f};

  const ushort* va = kT + ((size_t)b * 1024 + m0) * 256;
  const ushort* pa = qT + ((size_t)b * 1024 + j0) * 256;

  int srow[4], skc[4];
#pragma unroll
  for (int n = 0; n < 4; ++n) {
    int slot = wave * 256 + n * 64 + lane;
    srow[n] = slot >> 3;
    skc[n] = (slot & 7) ^ (srow[n] & 7);
  }

  // prologue: K-step 0 -> buffer 0
#pragma unroll
  for (int n = 0; n < 4; ++n) {
    async_copy16(va + (size_t)srow[n] * 256 + skc[n] * 8,
                 &smem[(wave * 256 + n * 64) * 8]);
    async_copy16(pa + (size_t)srow[n] * 256 + skc[n] * 8,
                 &smem[8192 + (wave * 256 + n * 64) * 8]);
  }
  __syncthreads();

  for (int t = 0; t < 4; ++t) {
    int cur = (t & 1) * 16384;
    int nxt = 16384 - cur;
    if (t < 3) {
      int kk = (t + 1) * 64;
#pragma unroll
      for (int n = 0; n < 4; ++n) {
        async_copy16(va + (size_t)srow[n] * 256 + kk + skc[n] * 8,
                     &smem[nxt + (wave * 256 + n * 64) * 8]);
        async_copy16(pa + (size_t)srow[n] * 256 + kk + skc[n] * 8,
                     &smem[nxt + 8192 + (wave * 256 + n * 64) * 8]);
      }
    }
#pragma unroll
    for (int ks = 0; ks < 2; ++ks) {
      short8 af[4], bfr[4];
#pragma unroll
      for (int s = 0; s < 4; ++s) {
        int row = wm * 64 + s * 16 + ml;
        int c = ks * 4 + quad;
        af[s] = *(const short8*)&smem[cur + (row * 8 + (c ^ (row & 7))) * 8];
      }
#pragma unroll
      for (int t2 = 0; t2 < 4; ++t2) {
        int row = wj * 64 + t2 * 16 + ml;
        int c = ks * 4 + quad;
        bfr[t2] = *(const short8*)&smem[cur + 8192 + (row * 8 + (c ^ (row & 7))) * 8];
      }
#pragma unroll
      for (int s = 0; s < 4; ++s)
#pragma unroll
        for (int t2 = 0; t2 < 4; ++t2)
          acc[s][t2] = __builtin_amdgcn_mfma_f32_16x16x32_bf16(af[s], bfr[t2], acc[s][t2], 0, 0, 0);
    }
    __syncthreads();
  }

  // ---- epilogue: P = exp(S); partial row sums over this block's 128 cols
#pragma unroll
  for (int s = 0; s < 4; ++s)
#pragma unroll
    for (int r = 0; r < 4; ++r) {
      float sum = 0.f;
#pragma unroll
      for (int t2 = 0; t2 < 4; ++t2) {
        float p = __expf(acc[s][t2][r]);
        acc[s][t2][r] = p;
        sum += p;
      }
      sum += __shfl_xor(sum, 1);
      sum += __shfl_xor(sum, 2);
      sum += __shfl_xor(sum, 4);
      sum += __shfl_xor(sum, 8);
      if (ml == 0) {
        int m = m0 + wm * 64 + s * 16 + quad * 4 + r;
        atomicAdd(&rsum[b * 1024 + m], sum);
      }
    }
  // store unnormalized P (bf16)
#pragma unroll
  for (int s = 0; s < 4; ++s)
#pragma unroll
    for (int t2 = 0; t2 < 4; ++t2) {
      int j = j0 + wj * 64 + t2 * 16 + ml;
#pragma unroll
      for (int r = 0; r < 4; ++r) {
        int m = m0 + wm * 64 + s * 16 + quad * 4 + r;
        A_p[((size_t)b * 1024 + m) * 1024 + j] = f2bf(acc[s][t2][r]);
      }
    }
}

// ---------------------------------------------------------------------------
// ad_part: partial S_d[b][dj][e] sums over hw-quarters (grid 8x16x4 = 512
// blocks, 4x the old ad parallelism; old ad left half the GPU idle).
// ---------------------------------------------------------------------------
__global__ __launch_bounds__(256) void ad_part_kernel(
    const float* __restrict__ k, const float* __restrict__ q,
    float* __restrict__ Sd) {
  int tid = threadIdx.x;
  int b = blockIdx.x;
  int dj = blockIdx.y;
  int split = blockIdx.z;
  float acc[16];
#pragma unroll
  for (int e = 0; e < 16; ++e) acc[e] = 0.f;
  const float* kb = k + (size_t)b * 256 * HW;
  const float* qb = q + (size_t)b * 256 * HW;
  int fend = (split + 1) * 4096;
  for (int f = split * 4096 + tid; f < fend; f += 256) {
    int oc = f >> 10, hw = f & 1023;
    float kv = kb[(oc * 16 + dj) * HW + hw];
#pragma unroll
    for (int e = 0; e < 16; ++e)
      acc[e] += kv * qb[(oc * 16 + e) * HW + hw];
  }
  int lane = tid & 63;
#pragma unroll
  for (int e = 0; e < 16; ++e) {
    float s = acc[e];
    for (int off = 32; off >= 1; off >>= 1) s += __shfl_xor(s, off);
    if (lane == 0) atomicAdd(&Sd[b * 256 + dj * 16 + e], s);
  }
}

// ---------------------------------------------------------------------------
// ad_fin: softmax over the 16 e's of each (b,dj) row.
// ---------------------------------------------------------------------------
__global__ __launch_bounds__(128) void ad_fin_kernel(
    const float* __restrict__ Sd, float* __restrict__ A_d) {
  int t = threadIdx.x;  // one (b,dj) row per thread, 128 rows
  const float* row = Sd + (size_t)t * 16;
  float m = row[0];
#pragma unroll
  for (int e = 1; e < 16; ++e) m = fmaxf(m, row[e]);
  float p[16], s = 0.f;
#pragma unroll
  for (int e = 0; e < 16; ++e) { p[e] = __expf(row[e] - m); s += p[e]; }
  float inv = 1.f / s;
#pragma unroll
  for (int e = 0; e < 16; ++e) A_d[(size_t)t * 16 + e] = p[e] * inv;
}

// ---------------------------------------------------------------------------
// combine: Patt = vf @ P^T / rowsum via bf16 MFMA + fused Datt + residual.
// ---------------------------------------------------------------------------
__global__ __launch_bounds__(256, 2) void combine_mfma_kernel(
    const ushort* __restrict__ vb, const ushort* __restrict__ apb,
    const float* __restrict__ A_d, const float* __restrict__ rsum,
    const float* __restrict__ x, const float* __restrict__ gamma,
    float* __restrict__ out) {
  __shared__ __align__(16) ushort smem[32768];
  __shared__ float Adt[272];  // A_d transposed, padded: Adt[d*17 + dj]
  int tid = threadIdx.x;
  int wave = tid >> 6, lane = tid & 63;
  int ml = lane & 15, quad = lane >> 4;
  int wm = wave >> 1, wj = wave & 1;
  int b = blockIdx.x;                    // XCD = wg_linear % 8 = b
  int tile = blockIdx.y;
  int m0 = (tile >> 3) * 128;            // m outer
  int j0 = (tile & 7) * 128;             // j inner
  Adt[(tid & 15) * 17 + (tid >> 4)] = A_d[b * 256 + tid];

  f32x4 acc[4][4];
#pragma unroll
  for (int s = 0; s < 4; ++s)
#pragma unroll
    for (int t = 0; t < 4; ++t) acc[s][t] = (f32x4){0.f, 0.f, 0.f, 0.f};

  const ushort* va = vb + ((size_t)b * 2048 + m0) * 1024;
  const ushort* pa = apb + ((size_t)b * 1024 + j0) * 1024;

  int srow[4], skc[4];
#pragma unroll
  for (int n = 0; n < 4; ++n) {
    int slot = wave * 256 + n * 64 + lane;
    srow[n] = slot >> 3;
    skc[n] = (slot & 7) ^ (srow[n] & 7);
  }

  // prologue: K-tile 0 -> buffer 0
#pragma unroll
  for (int n = 0; n < 4; ++n) {
    async_copy16(va + (size_t)srow[n] * 1024 + skc[n] * 8,
                 &smem[(wave * 256 + n * 64) * 8]);
    async_copy16(pa + (size_t)srow[n] * 1024 + skc[n] * 8,
                 &smem[8192 + (wave * 256 + n * 64) * 8]);
  }
  __syncthreads();

  for (int t = 0; t < 16; ++t) {
    int cur = (t & 1) * 16384;
    int nxt = 16384 - cur;
    if (t < 15) {
      int kk = (t + 1) * 64;
#pragma unroll
      for (int n = 0; n < 4; ++n) {
        async_copy16(va + (size_t)srow[n] * 1024 + kk + skc[n] * 8,
                     &smem[nxt + (wave * 256 + n * 64) * 8]);
        async_copy16(pa + (size_t)srow[n] * 1024 + kk + skc[n] * 8,
                     &smem[nxt + 8192 + (wave * 256 + n * 64) * 8]);
      }
    }
#pragma unroll
    for (int ks = 0; ks < 2; ++ks) {
      short8 af[4], bfr[4];
#pragma unroll
      for (int s = 0; s < 4; ++s) {
        int row = wm * 64 + s * 16 + ml;
        int c = ks * 4 + quad;
        af[s] = *(const short8*)&smem[cur + (row * 8 + (c ^ (row & 7))) * 8];
      }
#pragma unroll
      for (int t2 = 0; t2 < 4; ++t2) {
        int row = wj * 64 + t2 * 16 + ml;
        int c = ks * 4 + quad;
        bfr[t2] = *(const short8*)&smem[cur + 8192 + (row * 8 + (c ^ (row & 7))) * 8];
      }
#pragma unroll
      for (int s = 0; s < 4; ++s)
#pragma unroll
        for (int t2 = 0; t2 < 4; ++t2)
          acc[s][t2] = __builtin_amdgcn_mfma_f32_16x16x32_bf16(af[s], bfr[t2], acc[s][t2], 0, 0, 0);
    }
    __syncthreads();
  }

  // ---- normalize Patt by softmax row sums (apx stored unnormalized P)
  float invr[4];
#pragma unroll
  for (int t2 = 0; t2 < 4; ++t2)
    invr[t2] = 1.f / rsum[b * 1024 + j0 + wj * 64 + t2 * 16 + ml];
#pragma unroll
  for (int s = 0; s < 4; ++s)
#pragma unroll
    for (int t2 = 0; t2 < 4; ++t2)
#pragma unroll
      for (int r = 0; r < 4; ++r) acc[s][t2][r] *= invr[t2];

  // ---- epilogue: stage v[m0:+128][j0:+128] bf16 into smem (stride 136)
  for (int i = tid; i < 2048; i += 256) {
    int row = i >> 4, jc = i & 15;
    uint4 val = *(const uint4*)&vb[((size_t)b * 2048 + m0 + row) * 1024 + j0 + jc * 8];
    *(uint4*)&smem[row * 136 + jc * 8] = val;
  }
  __syncthreads();

  // Datt accumulated directly into acc; d-outer, conflict-free Adt.
#pragma unroll
  for (int d = 0; d < 16; ++d) {
    float ar[4];
#pragma unroll
    for (int r = 0; r < 4; ++r) ar[r] = Adt[d * 17 + quad * 4 + r];
#pragma unroll
    for (int s = 0; s < 4; ++s) {
      const ushort* vrow = &smem[(wm * 64 + s * 16 + d) * 136];
#pragma unroll
      for (int t2 = 0; t2 < 4; ++t2) {
        float vv = bf2f(vrow[wj * 64 + t2 * 16 + ml]);
#pragma unroll
        for (int r = 0; r < 4; ++r) acc[s][t2][r] += ar[r] * vv;
      }
    }
  }

  float g = gamma[0];
#pragma unroll
  for (int s = 0; s < 4; ++s) {
#pragma unroll
    for (int t2 = 0; t2 < 4; ++t2) {
      int jrel = wj * 64 + t2 * 16 + ml;
#pragma unroll
      for (int r = 0; r < 4; ++r) {
        int m = m0 + wm * 64 + s * 16 + quad * 4 + r;
        size_t idx = ((size_t)b * 2048 + m) * 1024 + j0 + jrel;
        out[idx] = g * acc[s][t2][r] + x[idx];
      }
    }
  }
}

// ---------------------------------------------------------------------------
extern "C" void kernel_launch(void* const* d_in, const int* in_sizes, int n_in,
                              void* d_out, int out_size, void* d_ws, size_t ws_size,
                              hipStream_t stream) {
  const float* x     = (const float*)d_in[0];
  const float* gamma = (const float*)d_in[1];
  const float* w_k   = (const float*)d_in[2];
  const float* b_k   = (const float*)d_in[3];
  const float* w_q   = (const float*)d_in[4];
  const float* b_q   = (const float*)d_in[5];
  const float* w_v   = (const float*)d_in[6];
  const float* b_v   = (const float*)d_in[7];
  float* out = (float*)d_out;

  float* k    = (float*)d_ws;            // 2,097,152 f32
  float* q    = k + 2097152;             // 2,097,152 f32
  float* A_d  = q + 2097152;             // 2,048 f32
  ushort* vbf = (ushort*)(A_d + 2048);   // 16,777,216 bf16
  ushort* apb = vbf + 16777216;          // 8,388,608 bf16
  ushort* wt  = apb + 8388608;           // 442,368 bf16
  ushort* zbuf = wt + 442368;            // 512 bf16 zeros
  ushort* xt  = zbuf + 512;              // 16,777,216 bf16
  // xt region is dead after vconv -> reuse for kT/qT/rsum/Sd:
  ushort* kT16 = xt;                     // 2,097,152 bf16
  ushort* qT16 = xt + 2097152;           // 2,097,152 bf16
  float* rsum  = (float*)(xt + 4194304); // 8,192 f32
  float* Sd    = rsum + 8192;            // 2,048 f32

  wprep_kernel<<<dim3(1728), 256, 0, stream>>>(w_v, wt, zbuf);
  kq_kernel<<<dim3(64, 8), 256, 0, stream>>>(x, w_k, b_k, w_q, b_q, k, q, xt);
  vconv_mfma_kernel<<<dim3(128, 4, 2), 256, 0, stream>>>(xt, wt, b_v, zbuf, vbf);
  kqt_kernel<<<dim3(32, 8), 256, 0, stream>>>(k, q, kT16, qT16, rsum, Sd);
  apx_kernel<<<dim3(8, 64), 256, 0, stream>>>(kT16, qT16, apb, rsum);
  ad_part_kernel<<<dim3(8, 16, 4), 256, 0, stream>>>(k, q, Sd);
  ad_fin_kernel<<<dim3(1), 128, 0, stream>>>(Sd, A_d);
  combine_mfma_kernel<<<dim3(8, 128), 256, 0, stream>>>(vbf, apb, A_d, rsum, x, gamma, out);
}

// Round 9
// 333.230 us; speedup vs baseline: 1.2702x; 1.1223x over previous
//
#include <hip/hip_runtime.h>

#define HW   1024
#define DHW  16384

typedef __attribute__((ext_vector_type(8))) short short8;
typedef __attribute__((ext_vector_type(4))) float f32x4;

static __device__ __forceinline__ ushort f2bf(float f) {
  unsigned u = __float_as_uint(f);
  unsigned r = (u + 0x7fffu + ((u >> 16) & 1u)) >> 16;
  return (ushort)r;
}
static __device__ __forceinline__ float bf2f(ushort u) {
  return __uint_as_float(((unsigned)u) << 16);
}
static __device__ __forceinline__ void async_copy16(const ushort* g, ushort* l) {
  __builtin_amdgcn_global_load_lds(
      (const __attribute__((address_space(1))) unsigned int*)g,
      (__attribute__((address_space(3))) unsigned int*)l, 16, 0, 0);
}

// ---------------------------------------------------------------------------
// prep: fat kernel = kq (1x1x1 conv + x->xt bf16 repack) U wprep.
// Blocks [0,512): kq; blocks [512,2240): wprep. One dispatch instead of two.
// kq weight LDS transposed to [c][o]: 4x ds_read_b128 broadcast per c
// (was 16x ds_read_b32) -- identical math.
// ---------------------------------------------------------------------------
__global__ __launch_bounds__(256) void prep_kernel(
    const float* __restrict__ x, const float* __restrict__ wk,
    const float* __restrict__ bk, const float* __restrict__ wq,
    const float* __restrict__ bq, const float* __restrict__ wv,
    float* __restrict__ k, float* __restrict__ q,
    ushort* __restrict__ xt, ushort* __restrict__ wt,
    ushort* __restrict__ zbuf) {
  __shared__ float wks[2048];  // [c][o]
  __shared__ float wqs[2048];
  int gid = blockIdx.x;
  int tid = threadIdx.x;
  if (gid >= 512) {
    // ---- wprep part: wt2[kd][chunk][tap][o][8c] <- wv[o][c][kd,kh,kw]
    if (gid == 512 && tid < 512) zbuf[tid] = 0;
    int i = (gid - 512) * 256 + tid;
    int c8 = i & 7;
    int t = i >> 3;
    int o = t & 127; t >>= 7;
    int tap = t % 9; t /= 9;
    int chunk = t & 15;
    int kd = t >> 4;
    wt[i] = f2bf(wv[(size_t)(o * 128 + chunk * 8 + c8) * 27 + kd * 9 + tap]);
    return;
  }
  // ---- kq part
  for (int i = tid; i < 2048; i += 256) {
    int c = i >> 4, o = i & 15;
    wks[i] = wk[o * 128 + c];
    wqs[i] = wq[o * 128 + c];
  }
  __syncthreads();
  int b = gid >> 6, bx = gid & 63;
  int p = bx * 256 + tid;
  int z = p >> 10, hw = p & 1023;
  float ak[16], aq[16];
#pragma unroll
  for (int o = 0; o < 16; ++o) { ak[o] = 0.f; aq[o] = 0.f; }
  const float* xb = x + (size_t)b * 128 * DHW + p;
  ushort* xtp = xt + (((size_t)(b * 16 + z) * 16) * 1024 + hw) * 8;
  for (int chunk = 0; chunk < 16; ++chunk) {
    ushort pack[8];
#pragma unroll
    for (int c8 = 0; c8 < 8; ++c8) {
      int c = chunk * 8 + c8;
      float xv = xb[(size_t)c * DHW];
      pack[c8] = f2bf(xv);
      const float4* wkc = (const float4*)&wks[c * 16];
      const float4* wqc = (const float4*)&wqs[c * 16];
#pragma unroll
      for (int g = 0; g < 4; ++g) {
        float4 wa = wkc[g], wb = wqc[g];
        ak[g * 4 + 0] += wa.x * xv; ak[g * 4 + 1] += wa.y * xv;
        ak[g * 4 + 2] += wa.z * xv; ak[g * 4 + 3] += wa.w * xv;
        aq[g * 4 + 0] += wb.x * xv; aq[g * 4 + 1] += wb.y * xv;
        aq[g * 4 + 2] += wb.z * xv; aq[g * 4 + 3] += wb.w * xv;
      }
    }
    *(uint4*)&xtp[(size_t)chunk * 1024 * 8] = *(const uint4*)pack;
  }
#pragma unroll
  for (int o = 0; o < 16; ++o) {
    k[((size_t)b * 16 + o) * DHW + p] = ak[o] + bk[o];
    q[((size_t)b * 16 + o) * DHW + p] = aq[o] + bq[o];
  }
}

// ---------------------------------------------------------------------------
// v 3x3x3 conv as implicit-GEMM bf16 MFMA (verified 98.5us config).
// b = bz&7 so XCD = b. Cross-block overlap provides stage/MFMA pipelining
// (m114); intra-block dbuf regressed (r5); bigger acc tiles spill (r7).
// SQ_LDS_BANK_CONFLICT ~7.1M is the intrinsic ~2cyc/wave-b128 floor.
// ---------------------------------------------------------------------------
__global__ __launch_bounds__(256, 2) void vconv_mfma_kernel(
    const ushort* __restrict__ xt, const ushort* __restrict__ wt,
    const float* __restrict__ bv, const ushort* __restrict__ zbuf,
    ushort* __restrict__ v) {
  __shared__ __align__(16) ushort xs[1536 * 8];
  __shared__ __align__(16) ushort wsm[2304 * 8];
  int tid = threadIdx.x;
  int wave = tid >> 6;
  int ml = tid & 15;
  int quad = (tid >> 4) & 3;
  int bz = blockIdx.x;
  int b = bz & 7, z = bz >> 3;           // XCD-locality decode (v4)
  int h0 = blockIdx.y * 8;
  int o0 = blockIdx.z * 64;

  f32x4 acc[4][4];
#pragma unroll
  for (int s = 0; s < 4; ++s)
#pragma unroll
    for (int t = 0; t < 4; ++t) acc[s][t] = (f32x4){0.f, 0.f, 0.f, 0.f};

  int cb0[4];
#pragma unroll
  for (int t = 0; t < 4; ++t)
    cb0[t] = (wave * 2 + (t >> 1)) * 34 + (t & 1) * 16 + ml;

  int xoff[6]; bool okx[6];
#pragma unroll
  for (int it = 0; it < 6; ++it) {
    int i = it * 256 + tid;
    int cu = i / 340;
    int cell = i - cu * 340;
    int hr = cell / 34;
    int wc = cell - hr * 34;
    int h = h0 + hr - 1, ww = wc - 1;
    okx[it] = (i < 1360) && ((unsigned)h < 32u) && ((unsigned)ww < 32u);
    xoff[it] = cu * 1024 + h * 32 + ww;
  }
  int woff[9];
#pragma unroll
  for (int it = 0; it < 9; ++it) {
    int i = it * 256 + tid;
    int cu = i / 576;
    int r = i - cu * 576;
    int tap = r >> 6, ol = r & 63;
    woff[it] = (cu * 9 + tap) * 128 + o0 + ol;
  }

  const int KH[9] = {0, 0, 0, 1, 1, 1, 2, 2, 2};
  const int KW[9] = {0, 1, 2, 0, 1, 2, 0, 1, 2};

  for (int kd = 0; kd < 3; ++kd) {
    int zd = z + kd - 1;
    bool zok = (zd >= 0 && zd < 16);
    int zdc = zok ? zd : 0;
    const ushort* xbase = xt + (size_t)(b * 16 + zdc) * 16 * 1024 * 8;
    for (int cb = 0; cb < 4; ++cb) {
      const ushort* xsb = xbase + (size_t)cb * 4 * 1024 * 8;
      const ushort* wsb = wt + (size_t)(kd * 16 + cb * 4) * 9 * 128 * 8;
#pragma unroll
      for (int it = 0; it < 6; ++it) {
        const ushort* g = (zok && okx[it]) ? xsb + (size_t)xoff[it] * 8 : zbuf;
        async_copy16(g, &xs[(it * 256 + tid) * 8]);
      }
#pragma unroll
      for (int it = 0; it < 9; ++it)
        async_copy16(wsb + (size_t)woff[it] * 8, &wsm[(it * 256 + tid) * 8]);
      __syncthreads();
#pragma unroll
      for (int tap = 0; tap < 9; ++tap) {
        const int kh = KH[tap], kw = KW[tap];
        short8 af[4], bfr[4];
#pragma unroll
        for (int s = 0; s < 4; ++s)
          af[s] = *(const short8*)&wsm[(quad * 576 + tap * 64 + s * 16 + ml) * 8];
#pragma unroll
        for (int t = 0; t < 4; ++t) {
          int cell = cb0[t] + kh * 34 + kw;
          bfr[t] = *(const short8*)&xs[(quad * 340 + cell) * 8];
        }
#pragma unroll
        for (int s = 0; s < 4; ++s)
#pragma unroll
          for (int t = 0; t < 4; ++t)
            acc[s][t] = __builtin_amdgcn_mfma_f32_16x16x32_bf16(af[s], bfr[t], acc[s][t], 0, 0, 0);
      }
      __syncthreads();
    }
  }
#pragma unroll
  for (int s = 0; s < 4; ++s) {
    int o = o0 + s * 16 + quad * 4;
#pragma unroll
    for (int t = 0; t < 4; ++t) {
      int pl = wave * 64 + t * 16 + ml;
      ushort* dst = &v[((size_t)(b * 128 + o) * 16 + z) * 1024 + h0 * 32 + pl];
#pragma unroll
      for (int r = 0; r < 4; ++r)
        dst[(size_t)r * 16384] = f2bf(acc[s][t][r] + bv[o + r]);
    }
  }
}

// ---------------------------------------------------------------------------
// kqt: transpose k,q (fp32 [b][o][z][hw]) -> bf16 kT/qT [b][hw][f=o*16+z]
// via LDS tiles; zeroes rsum and Sd (runs after vconv: kT/qT/rsum/Sd alias
// the then-dead xt region).
// ---------------------------------------------------------------------------
__global__ __launch_bounds__(256) void kqt_kernel(
    const float* __restrict__ k, const float* __restrict__ q,
    ushort* __restrict__ kT, ushort* __restrict__ qT,
    float* __restrict__ rsum, float* __restrict__ Sd) {
  __shared__ __align__(16) ushort tile[32 * 264];
  int tid = threadIdx.x;
  int t0 = blockIdx.x;   // hw tile 0..31
  int b = blockIdx.y;    // 0..7
  if (t0 == 0) {
    *(float4*)&rsum[b * 1024 + tid * 4] = (float4){0.f, 0.f, 0.f, 0.f};
    Sd[b * 256 + tid] = 0.f;
  }
  int h0 = t0 * 32;

  // ---- k pass
  {
    const float* s = k + (size_t)b * 16 * DHW;
    for (int it = 0; it < 32; ++it) {
      int i = it * 256 + tid;
      int oo = i >> 9, zz = (i >> 5) & 15, hl = i & 31;
      tile[hl * 264 + oo * 16 + zz] =
          f2bf(s[(size_t)oo * DHW + zz * 1024 + h0 + hl]);
    }
    __syncthreads();
    ushort* d = kT + ((size_t)b * 1024 + h0) * 256;
    for (int jt = 0; jt < 4; ++jt) {
      int j = jt * 256 + tid;
      int hl = j >> 5, c8 = (j & 31) * 8;
      *(uint4*)&d[(size_t)hl * 256 + c8] = *(const uint4*)&tile[hl * 264 + c8];
    }
    __syncthreads();
  }
  // ---- q pass
  {
    const float* s = q + (size_t)b * 16 * DHW;
    for (int it = 0; it < 32; ++it) {
      int i = it * 256 + tid;
      int oo = i >> 9, zz = (i >> 5) & 15, hl = i & 31;
      tile[hl * 264 + oo * 16 + zz] =
          f2bf(s[(size_t)oo * DHW + zz * 1024 + h0 + hl]);
    }
    __syncthreads();
    ushort* d = qT + ((size_t)b * 1024 + h0) * 256;
    for (int jt = 0; jt < 4; ++jt) {
      int j = jt * 256 + tid;
      int hl = j >> 5, c8 = (j & 31) * 8;
      *(uint4*)&d[(size_t)hl * 256 + c8] = *(const uint4*)&tile[hl * 264 + c8];
    }
  }
}

// ---------------------------------------------------------------------------
// att: fat kernel = apx (S=K^T Q MFMA + exp + rowsum atomics) U ad_part
// (partial depth-score sums). Grid (8,128): by<64 -> apx tile, by>=64 ->
// ad_part (dj = t&15, split = t>>4). Both paths keep XCD = b affinity.
// ---------------------------------------------------------------------------
__global__ __launch_bounds__(256, 2) void att_kernel(
    const ushort* __restrict__ kT, const ushort* __restrict__ qT,
    ushort* __restrict__ A_p, float* __restrict__ rsum,
    const float* __restrict__ k, const float* __restrict__ q,
    float* __restrict__ Sd) {
  __shared__ __align__(16) ushort smem[32768];
  int tid = threadIdx.x;
  int b = blockIdx.x;
  int by = blockIdx.y;

  if (by >= 64) {
    // ---- ad_part
    int t = by - 64;
    int dj = t & 15, split = t >> 4;
    float acc[16];
#pragma unroll
    for (int e = 0; e < 16; ++e) acc[e] = 0.f;
    const float* kb = k + (size_t)b * 256 * HW;
    const float* qb = q + (size_t)b * 256 * HW;
    int fend = (split + 1) * 4096;
    for (int f = split * 4096 + tid; f < fend; f += 256) {
      int oc = f >> 10, hw = f & 1023;
      float kv = kb[(oc * 16 + dj) * HW + hw];
#pragma unroll
      for (int e = 0; e < 16; ++e)
        acc[e] += kv * qb[(oc * 16 + e) * HW + hw];
    }
    int lane = tid & 63;
#pragma unroll
    for (int e = 0; e < 16; ++e) {
      float s = acc[e];
      for (int off = 32; off >= 1; off >>= 1) s += __shfl_xor(s, off);
      if (lane == 0) atomicAdd(&Sd[b * 256 + dj * 16 + e], s);
    }
    return;
  }

  // ---- apx
  int wave = tid >> 6, lane = tid & 63;
  int ml = lane & 15, quad = lane >> 4;
  int wm = wave >> 1, wj = wave & 1;
  int tile = by;
  int m0 = (tile >> 3) * 128;   // s-rows (softmax rows)
  int j0 = (tile & 7) * 128;    // t-cols

  f32x4 acc[4][4];
#pragma unroll
  for (int s = 0; s < 4; ++s)
#pragma unroll
    for (int t = 0; t < 4; ++t) acc[s][t] = (f32x4){0.f, 0.f, 0.f, 0.f};

  const ushort* va = kT + ((size_t)b * 1024 + m0) * 256;
  const ushort* pa = qT + ((size_t)b * 1024 + j0) * 256;

  int srow[4], skc[4];
#pragma unroll
  for (int n = 0; n < 4; ++n) {
    int slot = wave * 256 + n * 64 + lane;
    srow[n] = slot >> 3;
    skc[n] = (slot & 7) ^ (srow[n] & 7);
  }

  // prologue: K-step 0 -> buffer 0
#pragma unroll
  for (int n = 0; n < 4; ++n) {
    async_copy16(va + (size_t)srow[n] * 256 + skc[n] * 8,
                 &smem[(wave * 256 + n * 64) * 8]);
    async_copy16(pa + (size_t)srow[n] * 256 + skc[n] * 8,
                 &smem[8192 + (wave * 256 + n * 64) * 8]);
  }
  __syncthreads();

  for (int t = 0; t < 4; ++t) {
    int cur = (t & 1) * 16384;
    int nxt = 16384 - cur;
    if (t < 3) {
      int kk = (t + 1) * 64;
#pragma unroll
      for (int n = 0; n < 4; ++n) {
        async_copy16(va + (size_t)srow[n] * 256 + kk + skc[n] * 8,
                     &smem[nxt + (wave * 256 + n * 64) * 8]);
        async_copy16(pa + (size_t)srow[n] * 256 + kk + skc[n] * 8,
                     &smem[nxt + 8192 + (wave * 256 + n * 64) * 8]);
      }
    }
#pragma unroll
    for (int ks = 0; ks < 2; ++ks) {
      short8 af[4], bfr[4];
#pragma unroll
      for (int s = 0; s < 4; ++s) {
        int row = wm * 64 + s * 16 + ml;
        int c = ks * 4 + quad;
        af[s] = *(const short8*)&smem[cur + (row * 8 + (c ^ (row & 7))) * 8];
      }
#pragma unroll
      for (int t2 = 0; t2 < 4; ++t2) {
        int row = wj * 64 + t2 * 16 + ml;
        int c = ks * 4 + quad;
        bfr[t2] = *(const short8*)&smem[cur + 8192 + (row * 8 + (c ^ (row & 7))) * 8];
      }
#pragma unroll
      for (int s = 0; s < 4; ++s)
#pragma unroll
        for (int t2 = 0; t2 < 4; ++t2)
          acc[s][t2] = __builtin_amdgcn_mfma_f32_16x16x32_bf16(af[s], bfr[t2], acc[s][t2], 0, 0, 0);
    }
    __syncthreads();
  }

  // ---- epilogue: P = exp(S); partial row sums over this block's 128 cols
#pragma unroll
  for (int s = 0; s < 4; ++s)
#pragma unroll
    for (int r = 0; r < 4; ++r) {
      float sum = 0.f;
#pragma unroll
      for (int t2 = 0; t2 < 4; ++t2) {
        float p = __expf(acc[s][t2][r]);
        acc[s][t2][r] = p;
        sum += p;
      }
      sum += __shfl_xor(sum, 1);
      sum += __shfl_xor(sum, 2);
      sum += __shfl_xor(sum, 4);
      sum += __shfl_xor(sum, 8);
      if (ml == 0) {
        int m = m0 + wm * 64 + s * 16 + quad * 4 + r;
        atomicAdd(&rsum[b * 1024 + m], sum);
      }
    }
  // store unnormalized P (bf16)
#pragma unroll
  for (int s = 0; s < 4; ++s)
#pragma unroll
    for (int t2 = 0; t2 < 4; ++t2) {
      int j = j0 + wj * 64 + t2 * 16 + ml;
#pragma unroll
      for (int r = 0; r < 4; ++r) {
        int m = m0 + wm * 64 + s * 16 + quad * 4 + r;
        A_p[((size_t)b * 1024 + m) * 1024 + j] = f2bf(acc[s][t2][r]);
      }
    }
}

// ---------------------------------------------------------------------------
// combine: Patt = vf @ P^T / rowsum via bf16 MFMA + fused Datt + residual.
// v7: A_d softmax computed inline from raw Sd (ad_fin kernel eliminated) --
// 16 threads, one 16-wide softmax each, between prologue barrier and K-loop.
// ---------------------------------------------------------------------------
__global__ __launch_bounds__(256, 2) void combine_mfma_kernel(
    const ushort* __restrict__ vb, const ushort* __restrict__ apb,
    const float* __restrict__ Sd, const float* __restrict__ rsum,
    const float* __restrict__ x, const float* __restrict__ gamma,
    float* __restrict__ out) {
  __shared__ __align__(16) ushort smem[32768];
  __shared__ float Sdl[256];
  __shared__ float Adt[272];  // A_d transposed, padded: Adt[d*17 + dj]
  int tid = threadIdx.x;
  int wave = tid >> 6, lane = tid & 63;
  int ml = lane & 15, quad = lane >> 4;
  int wm = wave >> 1, wj = wave & 1;
  int b = blockIdx.x;                    // XCD = wg_linear % 8 = b
  int tile = blockIdx.y;
  int m0 = (tile >> 3) * 128;            // m outer
  int j0 = (tile & 7) * 128;             // j inner
  Sdl[tid] = Sd[b * 256 + tid];

  f32x4 acc[4][4];
#pragma unroll
  for (int s = 0; s < 4; ++s)
#pragma unroll
    for (int t = 0; t < 4; ++t) acc[s][t] = (f32x4){0.f, 0.f, 0.f, 0.f};

  const ushort* va = vb + ((size_t)b * 2048 + m0) * 1024;
  const ushort* pa = apb + ((size_t)b * 1024 + j0) * 1024;

  int srow[4], skc[4];
#pragma unroll
  for (int n = 0; n < 4; ++n) {
    int slot = wave * 256 + n * 64 + lane;
    srow[n] = slot >> 3;
    skc[n] = (slot & 7) ^ (srow[n] & 7);
  }

  // prologue: K-tile 0 -> buffer 0
#pragma unroll
  for (int n = 0; n < 4; ++n) {
    async_copy16(va + (size_t)srow[n] * 1024 + skc[n] * 8,
                 &smem[(wave * 256 + n * 64) * 8]);
    async_copy16(pa + (size_t)srow[n] * 1024 + skc[n] * 8,
                 &smem[8192 + (wave * 256 + n * 64) * 8]);
  }
  __syncthreads();

  // inline A_d softmax (replaces ad_fin): row dj = tid, over 16 depth slots
  if (tid < 16) {
    float m = Sdl[tid * 16];
#pragma unroll
    for (int e = 1; e < 16; ++e) m = fmaxf(m, Sdl[tid * 16 + e]);
    float p[16], s = 0.f;
#pragma unroll
    for (int e = 0; e < 16; ++e) { p[e] = __expf(Sdl[tid * 16 + e] - m); s += p[e]; }
    float inv = 1.f / s;
#pragma unroll
    for (int e = 0; e < 16; ++e) Adt[e * 17 + tid] = p[e] * inv;
  }

  for (int t = 0; t < 16; ++t) {
    int cur = (t & 1) * 16384;
    int nxt = 16384 - cur;
    if (t < 15) {
      int kk = (t + 1) * 64;
#pragma unroll
      for (int n = 0; n < 4; ++n) {
        async_copy16(va + (size_t)srow[n] * 1024 + kk + skc[n] * 8,
                     &smem[nxt + (wave * 256 + n * 64) * 8]);
        async_copy16(pa + (size_t)srow[n] * 1024 + kk + skc[n] * 8,
                     &smem[nxt + 8192 + (wave * 256 + n * 64) * 8]);
      }
    }
#pragma unroll
    for (int ks = 0; ks < 2; ++ks) {
      short8 af[4], bfr[4];
#pragma unroll
      for (int s = 0; s < 4; ++s) {
        int row = wm * 64 + s * 16 + ml;
        int c = ks * 4 + quad;
        af[s] = *(const short8*)&smem[cur + (row * 8 + (c ^ (row & 7))) * 8];
      }
#pragma unroll
      for (int t2 = 0; t2 < 4; ++t2) {
        int row = wj * 64 + t2 * 16 + ml;
        int c = ks * 4 + quad;
        bfr[t2] = *(const short8*)&smem[cur + 8192 + (row * 8 + (c ^ (row & 7))) * 8];
      }
#pragma unroll
      for (int s = 0; s < 4; ++s)
#pragma unroll
        for (int t2 = 0; t2 < 4; ++t2)
          acc[s][t2] = __builtin_amdgcn_mfma_f32_16x16x32_bf16(af[s], bfr[t2], acc[s][t2], 0, 0, 0);
    }
    __syncthreads();
  }

  // ---- normalize Patt by softmax row sums (apx stored unnormalized P)
  float invr[4];
#pragma unroll
  for (int t2 = 0; t2 < 4; ++t2)
    invr[t2] = 1.f / rsum[b * 1024 + j0 + wj * 64 + t2 * 16 + ml];
#pragma unroll
  for (int s = 0; s < 4; ++s)
#pragma unroll
    for (int t2 = 0; t2 < 4; ++t2)
#pragma unroll
      for (int r = 0; r < 4; ++r) acc[s][t2][r] *= invr[t2];

  // ---- epilogue: stage v[m0:+128][j0:+128] bf16 into smem (stride 136)
  for (int i = tid; i < 2048; i += 256) {
    int row = i >> 4, jc = i & 15;
    uint4 val = *(const uint4*)&vb[((size_t)b * 2048 + m0 + row) * 1024 + j0 + jc * 8];
    *(uint4*)&smem[row * 136 + jc * 8] = val;
  }
  __syncthreads();

  // Datt accumulated directly into acc; d-outer, conflict-free Adt.
#pragma unroll
  for (int d = 0; d < 16; ++d) {
    float ar[4];
#pragma unroll
    for (int r = 0; r < 4; ++r) ar[r] = Adt[d * 17 + quad * 4 + r];
#pragma unroll
    for (int s = 0; s < 4; ++s) {
      const ushort* vrow = &smem[(wm * 64 + s * 16 + d) * 136];
#pragma unroll
      for (int t2 = 0; t2 < 4; ++t2) {
        float vv = bf2f(vrow[wj * 64 + t2 * 16 + ml]);
#pragma unroll
        for (int r = 0; r < 4; ++r) acc[s][t2][r] += ar[r] * vv;
      }
    }
  }

  float g = gamma[0];
#pragma unroll
  for (int s = 0; s < 4; ++s) {
#pragma unroll
    for (int t2 = 0; t2 < 4; ++t2) {
      int jrel = wj * 64 + t2 * 16 + ml;
#pragma unroll
      for (int r = 0; r < 4; ++r) {
        int m = m0 + wm * 64 + s * 16 + quad * 4 + r;
        size_t idx = ((size_t)b * 2048 + m) * 1024 + j0 + jrel;
        out[idx] = g * acc[s][t2][r] + x[idx];
      }
    }
  }
}

// ---------------------------------------------------------------------------
extern "C" void kernel_launch(void* const* d_in, const int* in_sizes, int n_in,
                              void* d_out, int out_size, void* d_ws, size_t ws_size,
                              hipStream_t stream) {
  const float* x     = (const float*)d_in[0];
  const float* gamma = (const float*)d_in[1];
  const float* w_k   = (const float*)d_in[2];
  const float* b_k   = (const float*)d_in[3];
  const float* w_q   = (const float*)d_in[4];
  const float* b_q   = (const float*)d_in[5];
  const float* w_v   = (const float*)d_in[6];
  const float* b_v   = (const float*)d_in[7];
  float* out = (float*)d_out;

  float* k    = (float*)d_ws;            // 2,097,152 f32
  float* q    = k + 2097152;             // 2,097,152 f32
  float* A_d  = q + 2097152;             // 2,048 f32 (unused slot, kept)
  ushort* vbf = (ushort*)(A_d + 2048);   // 16,777,216 bf16
  ushort* apb = vbf + 16777216;          // 8,388,608 bf16
  ushort* wt  = apb + 8388608;           // 442,368 bf16
  ushort* zbuf = wt + 442368;            // 512 bf16 zeros
  ushort* xt  = zbuf + 512;              // 16,777,216 bf16
  // xt region is dead after vconv -> reuse for kT/qT/rsum/Sd (kqt writes):
  ushort* kT16 = xt;                     // 2,097,152 bf16
  ushort* qT16 = xt + 2097152;           // 2,097,152 bf16
  float* rsum  = (float*)(xt + 4194304); // 8,192 f32
  float* Sd    = rsum + 8192;            // 2,048 f32

  prep_kernel<<<dim3(2240), 256, 0, stream>>>(x, w_k, b_k, w_q, b_q, w_v,
                                              k, q, xt, wt, zbuf);
  vconv_mfma_kernel<<<dim3(128, 4, 2), 256, 0, stream>>>(xt, wt, b_v, zbuf, vbf);
  kqt_kernel<<<dim3(32, 8), 256, 0, stream>>>(k, q, kT16, qT16, rsum, Sd);
  att_kernel<<<dim3(8, 128), 256, 0, stream>>>(kT16, qT16, apb, rsum, k, q, Sd);
  combine_mfma_kernel<<<dim3(8, 128), 256, 0, stream>>>(vbf, apb, Sd, rsum, x, gamma, out);
}